// Round 2
// baseline (219.935 us; speedup 1.0000x reference)
//
#include <hip/hip_runtime.h>

typedef __attribute__((ext_vector_type(8))) __bf16 bf16x8;
typedef __attribute__((ext_vector_type(4))) float f32x4;

__device__ __forceinline__ bf16x8 cvt8(f32x4 a, f32x4 b) {
    bf16x8 v;
    v[0] = (__bf16)a.x; v[1] = (__bf16)a.y; v[2] = (__bf16)a.z; v[3] = (__bf16)a.w;
    v[4] = (__bf16)b.x; v[5] = (__bf16)b.y; v[6] = (__bf16)b.z; v[7] = (__bf16)b.w;
    return v;
}

// ---------------------------------------------------------------------------
// Kernel 0: zero the 512KB accumulator + build graph offsets from sorted batch.
// ---------------------------------------------------------------------------
__global__ void prep(const int* __restrict__ batch, int nN,
                     float* __restrict__ sums, int* __restrict__ off)
{
    const int i = blockIdx.x * blockDim.x + threadIdx.x;
    const int stride = gridDim.x * blockDim.x;
    for (int t = i; t < 1024 * 128; t += stride) sums[t] = 0.f;
    for (int t = i; t < nN; t += stride) {
        const int b  = batch[t];
        const int bp = (t == 0) ? -1 : batch[t - 1];
        for (int g = bp + 1; g <= b; ++g) off[g] = t;
        if (t == nN - 1) {
            for (int g = b + 1; g <= 1024; ++g) off[g] = nN;
        }
    }
}

// ---------------------------------------------------------------------------
// Kernel 1: barrier-free main loop. W (lin|gate) staged once to LDS as bf16
// [256 cols][128 k], XOR-swizzled. Each wave owns 16 nodes per chunk:
//   load x rows -> bf16 A-frags -> GEMM gates -> in-wave softmax ->
//   GEMM states -> gated -> segmented column-sum -> atomicAdd to sums.
// ---------------------------------------------------------------------------
__global__ __launch_bounds__(512, 4) void gnn_main(
    const float* __restrict__ x, const int* __restrict__ batch,
    const float* __restrict__ Wlin, const float* __restrict__ blin,
    const float* __restrict__ Wgate, const float* __restrict__ bgate,
    float* __restrict__ sums, int nN, int nIter)
{
    __shared__ __bf16 Wlds[256 * 128];   // 64 KB

    const int tid  = threadIdx.x;
    const int lane = tid & 63;
    const int w    = tid >> 6;    // wave 0..7
    const int l15  = lane & 15;
    const int lg   = lane >> 4;   // 0..3

    // ---- stage W -> LDS (bf16, swizzle: byte ^= (col&7)<<4)
    for (int idx = tid; idx < 4096; idx += 512) {
        const int c  = idx >> 4;      // col 0..255  (0-127 lin, 128-255 gate)
        const int kg = idx & 15;      // 8-elem k group
        const float* src = (c < 128 ? Wlin + (size_t)c * 128
                                    : Wgate + (size_t)(c - 128) * 128) + kg * 8;
        f32x4 u0 = *(const f32x4*)src;
        f32x4 u1 = *(const f32x4*)(src + 4);
        const int byte = (c * 256 + kg * 16) ^ ((c & 7) << 4);
        *(bf16x8*)((char*)Wlds + byte) = cvt8(u0, u1);
    }

    // per-lane biases for cols j*16 + l15
    float bl[8], bg[8];
#pragma unroll
    for (int j = 0; j < 8; ++j) {
        bl[j] = blin[j * 16 + l15];
        bg[j] = bgate[j * 16 + l15];
    }
    __syncthreads();   // the ONLY barrier

    for (int it = blockIdx.x; it < nIter; it += gridDim.x) {
        const int base = it * 128 + w * 16;      // this wave's 16 nodes
        if (base >= nN) continue;

        // ---- A fragments: row = l15, k = kk*32 + lg*8 + i  (clamped load)
        const int nodeA = base + l15;
        const float* xr = x + (size_t)(nodeA < nN ? nodeA : nN - 1) * 128;
        bf16x8 afr[4];
#pragma unroll
        for (int kk = 0; kk < 4; ++kk) {
            f32x4 u0 = *(const f32x4*)(xr + kk * 32 + lg * 8);
            f32x4 u1 = *(const f32x4*)(xr + kk * 32 + lg * 8 + 4);
            afr[kk] = cvt8(u0, u1);
        }

        // ---- pass 1: gate GEMM (cols 128..255)
        f32x4 e[8];
#pragma unroll
        for (int j = 0; j < 8; ++j) e[j] = (f32x4)0.f;
#pragma unroll
        for (int kk = 0; kk < 4; ++kk) {
#pragma unroll
            for (int j = 0; j < 8; ++j) {
                const int col  = 128 + j * 16 + l15;
                const int byte = (col * 256 + kk * 64 + lg * 16) ^ ((col & 7) << 4);
                bf16x8 bfr = *(const bf16x8*)((const char*)Wlds + byte);
                e[j] = __builtin_amdgcn_mfma_f32_16x16x32_bf16(afr[kk], bfr, e[j], 0, 0, 0);
            }
        }

        // ---- in-wave softmax (row = lg*4 + r, cols spread over l15 x j)
        f32x4 ps = (f32x4)0.f;
#pragma unroll
        for (int j = 0; j < 8; ++j) {
#pragma unroll
            for (int r = 0; r < 4; ++r) {
                float t = __expf(e[j][r] + bg[j]);
                e[j][r] = t;
                ps[r] += t;
            }
        }
        float inv[4];
#pragma unroll
        for (int r = 0; r < 4; ++r) {
            float p = ps[r];
            p += __shfl_xor(p, 1);
            p += __shfl_xor(p, 2);
            p += __shfl_xor(p, 4);
            p += __shfl_xor(p, 8);
            inv[r] = 1.0f / p;
        }

        // ---- pass 2: state GEMM (cols 0..127)
        f32x4 s[8];
#pragma unroll
        for (int j = 0; j < 8; ++j) s[j] = (f32x4)0.f;
#pragma unroll
        for (int kk = 0; kk < 4; ++kk) {
#pragma unroll
            for (int j = 0; j < 8; ++j) {
                const int col  = j * 16 + l15;
                const int byte = (col * 256 + kk * 64 + lg * 16) ^ ((col & 7) << 4);
                bf16x8 bfr = *(const bf16x8*)((const char*)Wlds + byte);
                s[j] = __builtin_amdgcn_mfma_f32_16x16x32_bf16(afr[kk], bfr, s[j], 0, 0, 0);
            }
        }

        // ---- gated values
#pragma unroll
        for (int j = 0; j < 8; ++j) {
#pragma unroll
            for (int r = 0; r < 4; ++r) {
                s[j][r] = (s[j][r] + bl[j]) * e[j][r] * inv[r];
            }
        }

        // ---- segmented column-sum + atomics (C rows: base + lg*4 + r)
        int bC[4];
#pragma unroll
        for (int r = 0; r < 4; ++r) {
            const int n = base + lg * 4 + r;
            bC[r] = (n < nN) ? batch[n] : -1;
        }
        const int gf = batch[base];
        const bool ok = (bC[0] == gf) & (bC[1] == gf) & (bC[2] == gf) & (bC[3] == gf);
        if (__all(ok)) {
#pragma unroll
            for (int j = 0; j < 8; ++j) {
                float cs = s[j][0] + s[j][1] + s[j][2] + s[j][3];
                cs += __shfl_xor(cs, 16);
                cs += __shfl_xor(cs, 32);
                if (lg == 0) atomicAdd(sums + (size_t)gf * 128 + j * 16 + l15, cs);
            }
        } else {
            int mn = 0x7fffffff, mx = -1;
#pragma unroll
            for (int r = 0; r < 4; ++r) {
                const int b = bC[r];
                if (b >= 0) { mn = min(mn, b); mx = max(mx, b); }
            }
#pragma unroll
            for (int d = 1; d < 64; d <<= 1) {
                mn = min(mn, __shfl_xor(mn, d));
                mx = max(mx, __shfl_xor(mx, d));
            }
            for (int g = mn; g <= mx; ++g) {
#pragma unroll
                for (int j = 0; j < 8; ++j) {
                    float cs = 0.f;
#pragma unroll
                    for (int r = 0; r < 4; ++r) cs += (bC[r] == g) ? s[j][r] : 0.f;
                    cs += __shfl_xor(cs, 16);
                    cs += __shfl_xor(cs, 32);
                    if (lg == 0) atomicAdd(sums + (size_t)g * 128 + j * 16 + l15, cs);
                }
            }
        }
    }
}

// ---------------------------------------------------------------------------
// Kernel 2: mean = sums/count, out = mean @ Wf^T + bf
// ---------------------------------------------------------------------------
__global__ __launch_bounds__(128) void final_mm(
    const float* __restrict__ sums, const int* __restrict__ off,
    const float* __restrict__ Wf, const float* __restrict__ bf,
    float* __restrict__ out)
{
    const int g = blockIdx.x, c = threadIdx.x;
    __shared__ float m[128];
    const int cnt = off[g + 1] - off[g];
    const float invC = 1.0f / (float)(cnt > 0 ? cnt : 1);
    m[c] = sums[g * 128 + c] * invC;
    __syncthreads();
    float acc = bf[c];
    const f32x4* wr = (const f32x4*)(Wf + (size_t)c * 128);
#pragma unroll
    for (int k = 0; k < 32; ++k) {
        f32x4 wv = wr[k];
        acc += m[4 * k] * wv.x + m[4 * k + 1] * wv.y + m[4 * k + 2] * wv.z + m[4 * k + 3] * wv.w;
    }
    out[g * 128 + c] = acc;
}

extern "C" void kernel_launch(void* const* d_in, const int* in_sizes, int n_in,
                              void* d_out, int out_size, void* d_ws, size_t ws_size,
                              hipStream_t stream)
{
    const float* x     = (const float*)d_in[0];
    const int*   batch = (const int*)d_in[1];
    const float* Wlin  = (const float*)d_in[2];
    const float* blin  = (const float*)d_in[3];
    const float* Wgate = (const float*)d_in[4];
    const float* bgate = (const float*)d_in[5];
    const float* Wfin  = (const float*)d_in[6];
    const float* bfin  = (const float*)d_in[7];
    float* out  = (float*)d_out;
    float* sums = (float*)d_ws;                               // 512 KB
    int*   off  = (int*)((char*)d_ws + 512 * 1024);           // 1025 ints

    const int nNodes  = in_sizes[1];
    const int nGraphs = out_size / 128;
    const int nIter   = (nNodes + 127) / 128;

    prep<<<2048, 256, 0, stream>>>(batch, nNodes, sums, off);
    gnn_main<<<512, 512, 0, stream>>>(x, batch, Wlin, blin, Wgate, bgate, sums, nNodes, nIter);
    final_mm<<<nGraphs, 128, 0, stream>>>(sums, off, Wfin, bfin, out);
}